// Round 5
// baseline (290.410 us; speedup 1.0000x reference)
//
#include <hip/hip_runtime.h>
#include <math.h>

// ---------------- problem constants ----------------
#define CIN   512
#define NOUT  123      // DEPTH + CT
#define OP    128      // padded row
#define DEPN  59
#define CT    64
#define B_    4
#define N_    6
#define FH    16
#define FW    44
#define HW    704      // FH*FW
#define NPIX  (B_*N_*HW)          // 16896
#define NX    128
#define BEV_ELEMS (B_*CT*NX*NX)   // 4,194,304
#define DEPTH_OFF BEV_ELEMS

// ws layout (float offsets). Double region first (8B aligned at base).
// Per-(b,n) transform record: 40 doubles:
//   [0..8] inv(post_rots)  [9..11] post_trans  [12..20] comb=rots@invK
//   [21..23] trans         [24..32] bda
#define TDREC   40
#define WS_WT   1920                       // transposed weight [512][128]
#define WS_OUT  (WS_WT + CIN*OP)           // [16896][128] conv output
#define WS_P    (WS_OUT + NPIX*OP)         // probs  [b][w][d][n*16+h]
#define WS_F    (WS_P + B_*FW*DEPN*96)     // feats  [b][w][n*16+h][64]

// ---------------- K0: weight transpose + per-(b,n) f64 transforms ----------------
__device__ inline void inv3d(const double* m, double* o) {
    #pragma clang fp contract(off)
    double c00 = m[4]*m[8] - m[5]*m[7];
    double c01 = m[5]*m[6] - m[3]*m[8];
    double c02 = m[3]*m[7] - m[4]*m[6];
    double det = m[0]*c00 + m[1]*c01 + m[2]*c02;
    o[0] = c00/det; o[1] = (m[2]*m[7]-m[1]*m[8])/det; o[2] = (m[1]*m[5]-m[2]*m[4])/det;
    o[3] = c01/det; o[4] = (m[0]*m[8]-m[2]*m[6])/det; o[5] = (m[2]*m[3]-m[0]*m[5])/det;
    o[6] = c02/det; o[7] = (m[1]*m[6]-m[0]*m[7])/det; o[8] = (m[0]*m[4]-m[1]*m[3])/det;
}
__device__ inline void mm3d(const double* a, const double* b, double* o) {
    #pragma clang fp contract(off)
    for (int i = 0; i < 3; ++i)
        for (int k = 0; k < 3; ++k)
            o[i*3+k] = (a[i*3+0]*b[0*3+k] + a[i*3+1]*b[1*3+k]) + a[i*3+2]*b[2*3+k];
}

__global__ void k0_prep(const float* __restrict__ rots, const float* __restrict__ trans,
                        const float* __restrict__ intr, const float* __restrict__ prots,
                        const float* __restrict__ ptrans, const float* __restrict__ bda,
                        const float* __restrict__ W, float* __restrict__ ws) {
    int tid = blockIdx.x * 256 + threadIdx.x;
    int stride = gridDim.x * 256;
    for (int i = tid; i < CIN * OP; i += stride) {
        int c = i >> 7, o = i & 127;
        ws[WS_WT + i] = (o < NOUT) ? W[o * CIN + c] : 0.0f;
    }
    if (blockIdx.x == 0 && threadIdx.x < B_ * N_) {
        #pragma clang fp contract(off)
        int t = threadIdx.x;
        int b = t / N_;
        double* X = (double*)(ws) + t * TDREC;
        double PR[9], Kd[9], Rd[9], Bd[9];
        for (int i = 0; i < 9; ++i) PR[i] = (double)prots[t * 9 + i];
        for (int i = 0; i < 9; ++i) Kd[i] = (double)intr[t * 9 + i];
        for (int i = 0; i < 9; ++i) Rd[i] = (double)rots[t * 9 + i];
        for (int i = 0; i < 9; ++i) Bd[i] = (double)bda[b * 9 + i];
        double iPR[9]; inv3d(PR, iPR);
        for (int i = 0; i < 9; ++i) X[i] = iPR[i];
        for (int i = 0; i < 3; ++i) X[9 + i] = (double)ptrans[t * 3 + i];
        double iK[9];  inv3d(Kd, iK);
        double comb[9]; mm3d(Rd, iK, comb);
        for (int i = 0; i < 9; ++i) X[12 + i] = comb[i];
        for (int i = 0; i < 3; ++i) X[21 + i] = (double)trans[t * 3 + i];
        for (int i = 0; i < 9; ++i) X[24 + i] = Bd[i];
    }
}

// ---------------- K1: 1x1 conv GEMM  out[pix][o] = x[.,c,pix] @ W[o,c] + bias --------
__global__ __launch_bounds__(256) void k1_gemm(const float* __restrict__ x,
                                               const float* __restrict__ bias,
                                               float* __restrict__ ws) {
    __shared__ float sx[32][32];    // [c][pix]
    __shared__ float sw[32][128];   // [c][o]
    const int tid = threadIdx.x;
    const int og4 = (tid & 31) * 4;
    const int pg4 = (tid >> 5) * 4;
    const int bn = blockIdx.y;
    const int hwbase = blockIdx.x * 32;
    const float* xg = x + (size_t)bn * CIN * HW + hwbase;
    const float* wT = ws + WS_WT;
    float acc[4][4] = {};
    for (int ck = 0; ck < CIN; ck += 32) {
        __syncthreads();
        { // stage x: 1024 floats
            int r = tid >> 3, c4 = (tid & 7) * 4;
            *(float4*)&sx[r][c4] = *(const float4*)(xg + (size_t)(ck + r) * HW + c4);
        }
        { // stage w: 4096 floats
            int o4 = (tid & 31) * 4, rb = tid >> 5;
            #pragma unroll
            for (int rr = 0; rr < 4; ++rr) {
                int r = rb + rr * 8;
                *(float4*)&sw[r][o4] = *(const float4*)(wT + (size_t)(ck + r) * OP + o4);
            }
        }
        __syncthreads();
        #pragma unroll
        for (int cc = 0; cc < 32; ++cc) {
            const float4 wv = *(const float4*)&sw[cc][og4];
            const float4 xv = *(const float4*)&sx[cc][pg4];
            acc[0][0] = fmaf(xv.x, wv.x, acc[0][0]); acc[0][1] = fmaf(xv.x, wv.y, acc[0][1]);
            acc[0][2] = fmaf(xv.x, wv.z, acc[0][2]); acc[0][3] = fmaf(xv.x, wv.w, acc[0][3]);
            acc[1][0] = fmaf(xv.y, wv.x, acc[1][0]); acc[1][1] = fmaf(xv.y, wv.y, acc[1][1]);
            acc[1][2] = fmaf(xv.y, wv.z, acc[1][2]); acc[1][3] = fmaf(xv.y, wv.w, acc[1][3]);
            acc[2][0] = fmaf(xv.z, wv.x, acc[2][0]); acc[2][1] = fmaf(xv.z, wv.y, acc[2][1]);
            acc[2][2] = fmaf(xv.z, wv.z, acc[2][2]); acc[2][3] = fmaf(xv.z, wv.w, acc[2][3]);
            acc[3][0] = fmaf(xv.w, wv.x, acc[3][0]); acc[3][1] = fmaf(xv.w, wv.y, acc[3][1]);
            acc[3][2] = fmaf(xv.w, wv.z, acc[3][2]); acc[3][3] = fmaf(xv.w, wv.w, acc[3][3]);
        }
    }
    float bb[4];
    #pragma unroll
    for (int j = 0; j < 4; ++j) bb[j] = (og4 + j < NOUT) ? bias[og4 + j] : 0.0f;
    float* out = ws + WS_OUT;
    #pragma unroll
    for (int i = 0; i < 4; ++i) {
        size_t pix = (size_t)bn * HW + hwbase + pg4 + i;
        float4 st = { acc[i][0] + bb[0], acc[i][1] + bb[1], acc[i][2] + bb[2], acc[i][3] + bb[3] };
        *(float4*)(out + pix * OP + og4) = st;
    }
}

// ---------------- K2a: per-pixel softmax, write depth + P/F scratch ----------------
__global__ __launch_bounds__(64) void k2a_softmax(float* __restrict__ ws, float* __restrict__ dout) {
    const int pix = blockIdx.x;
    const int lane = threadIdx.x;
    const float* row = ws + WS_OUT + (size_t)pix * OP;
    const int bn = pix / HW, hw = pix - bn * HW;
    const int b = bn / N_, n = bn - b * N_;
    const int h = hw / FW, w = hw - h * FW;
    const float v = row[lane];
    float m = (lane < DEPN) ? v : -INFINITY;
    #pragma unroll
    for (int off = 32; off > 0; off >>= 1) m = fmaxf(m, __shfl_xor(m, off, 64));
    float e = (lane < DEPN) ? expf(v - m) : 0.0f;
    float s = e;
    #pragma unroll
    for (int off = 32; off > 0; off >>= 1) s += __shfl_xor(s, off, 64);
    if (lane < DEPN) {
        float p = e / s;
        dout[DEPTH_OFF + (((size_t)bn * DEPN + lane) * FH + h) * FW + w] = p;
        ws[WS_P + ((size_t)(b * FW + w) * DEPN + lane) * 96 + n * FH + h] = p;
    }
    float f = row[59 + lane];
    ws[WS_F + ((size_t)(b * FW + w) * 96 + n * FH + h) * CT + lane] = f;
}

// ---------------- K2b: f64 geometry + voxel-aggregated scatter ----------------
// Binning chain validated against 3 rounds of error data (exact ulp analysis):
// f64 geometry (f32 inputs upcast), numerator constant = f32-upcast value of
// BX - DX/2 (-51.2000007629394531), divisor = NATIVE f64 0.8. This yields
// y-bins (75, 86, 97) at w=0 d={15,30,45} and x-bin (d+51.2)/0.8 exact.
__global__ __launch_bounds__(256) void k2b_scatter(const float* __restrict__ ws,
                                                   float* __restrict__ dout) {
    #pragma clang fp contract(off)
    __shared__ float  sF[96][64];
    __shared__ float  sP[8][96];
    __shared__ int    sv[8][96];
    __shared__ int    sflag[8];
    __shared__ double sxfd[N_ * TDREC];   // this b's 6 transform records
    const int tid = threadIdx.x;
    const int bw = blockIdx.x;
    const int b = bw / FW, w = bw - b * FW;
    const int d0 = blockIdx.y * 8;
    const int nd = min(8, DEPN - d0);

    { // feats: 6144 floats contiguous
        const float4* src = (const float4*)(ws + WS_F + (size_t)bw * (96 * 64));
        float4* dst = (float4*)&sF[0][0];
        for (int i = tid; i < 96 * 64 / 4; i += 256) dst[i] = src[i];
    }
    { // probs: nd*96 contiguous
        const float* src = ws + WS_P + ((size_t)bw * DEPN + d0) * 96;
        float* dst = &sP[0][0];
        for (int i = tid; i < nd * 96; i += 256) dst[i] = src[i];
    }
    if (tid < N_ * TDREC) sxfd[tid] = ((const double*)ws)[b * (N_ * TDREC) + tid];
    __syncthreads();

    if (tid < 96) {
        const int n = tid >> 4, h = tid & 15;
        const double* T = &sxfd[n * TDREC];
        // numpy linspace f64: y = w * fl(703/43); endpoint y[43] = 703.0
        const double xs = (w == 43) ? 703.0 : (double)w * (703.0 / 43.0);
        const double ys = (double)(h * 17);
        const double u0 = xs - T[9];
        const double u1 = ys - T[10];
        // numerator constant: f32 VALUE of BX-DX/2, upcast (validated R1-R4)
        const double BXY = (double)(-51.2000007629394531f);
        for (int ds = 0; ds < nd; ++ds) {
            const double dv = (double)(d0 + ds + 1);
            const double u2 = dv - T[11];
            // inv(post_rots) einsum (j-sequential)
            const double p0 = (T[0]*u0 + T[1]*u1) + T[2]*u2;
            const double p1 = (T[3]*u0 + T[4]*u1) + T[5]*u2;
            const double p2 = (T[6]*u0 + T[7]*u1) + T[8]*u2;
            const double q0 = p0 * p2;
            const double q1 = p1 * p2;
            const double q2 = p2;
            // comb einsum + trans
            const double r0 = ((T[12]*q0 + T[13]*q1) + T[14]*q2) + T[21];
            const double r1 = ((T[15]*q0 + T[16]*q1) + T[17]*q2) + T[22];
            const double r2 = ((T[18]*q0 + T[19]*q1) + T[20]*q2) + T[23];
            // bda einsum
            const double g0 = (T[24]*r0 + T[25]*r1) + T[26]*r2;
            const double g1 = (T[27]*r0 + T[28]*r1) + T[29]*r2;
            const double g2 = (T[30]*r0 + T[31]*r1) + T[32]*r2;
            // divisor: NATIVE f64 0.8 (not f32-upcast) — validated
            const double fx = floor((g0 - BXY) / 0.8);
            const double fy = floor((g1 - BXY) / 0.8);
            const double fz = floor((g2 + 10.0) / 20.0);
            const bool keep = (fx >= 0.0) & (fx < 128.0) & (fy >= 0.0) & (fy < 128.0) &
                              (fz >= 0.0) & (fz < 1.0);
            sv[ds][tid] = keep ? ((b * CT) << 14) + (int)fx * NX + (int)fy : -1;
        }
    }
    __syncthreads();
    if (tid < nd) {
        int u = -1; bool mix = false;
        for (int j = 0; j < 96; ++j) {
            int v = sv[tid][j];
            if (v >= 0) { if (u < 0) u = v; else if (v != u) mix = true; }
        }
        sflag[tid] = mix ? -2 : u;
    }
    __syncthreads();

    const int c = tid & 63, jb = (tid >> 6) * 24;
    for (int ds = 0; ds < nd; ++ds) {
        const int fl = sflag[ds];
        if (fl == -1) continue;
        if (fl >= 0) {
            float a = 0.0f;
            #pragma unroll 4
            for (int jj = 0; jj < 24; ++jj) {
                const int j = jb + jj;
                if (sv[ds][j] >= 0) a = fmaf(sP[ds][j], sF[j][c], a);
            }
            atomicAdd(dout + fl + (c << 14), a);
        } else { // generic fallback: per-point atomics
            for (int jj = 0; jj < 24; ++jj) {
                const int j = jb + jj;
                const int vv = sv[ds][j];
                if (vv >= 0) atomicAdd(dout + vv + (c << 14), sP[ds][j] * sF[j][c]);
            }
        }
    }
}

// ---------------- launcher ----------------
extern "C" void kernel_launch(void* const* d_in, const int* in_sizes, int n_in,
                              void* d_out, int out_size, void* d_ws, size_t ws_size,
                              hipStream_t stream) {
    const float* x      = (const float*)d_in[0];
    const float* rots   = (const float*)d_in[1];
    const float* trans  = (const float*)d_in[2];
    const float* intr   = (const float*)d_in[3];
    const float* prots  = (const float*)d_in[4];
    const float* ptrans = (const float*)d_in[5];
    const float* bda    = (const float*)d_in[6];
    const float* W      = (const float*)d_in[7];
    const float* bias   = (const float*)d_in[8];
    float* out = (float*)d_out;
    float* ws  = (float*)d_ws;

    hipMemsetAsync(d_out, 0, (size_t)BEV_ELEMS * sizeof(float), stream);
    k0_prep<<<128, 256, 0, stream>>>(rots, trans, intr, prots, ptrans, bda, W, ws);
    k1_gemm<<<dim3(HW / 32, B_ * N_), 256, 0, stream>>>(x, bias, ws);
    k2a_softmax<<<NPIX, 64, 0, stream>>>(ws, out);
    k2b_scatter<<<dim3(B_ * FW, 8), 256, 0, stream>>>(ws, out);
}

// Round 6
// 213.042 us; speedup vs baseline: 1.3632x; 1.3632x over previous
//
#include <hip/hip_runtime.h>
#include <math.h>

// ---------------- problem constants ----------------
#define CIN   512
#define NOUT  123      // DEPTH + CT
#define OP    128      // padded row
#define DEPN  59
#define CT    64
#define B_    4
#define N_    6
#define FH    16
#define FW    44
#define HW    704      // FH*FW
#define NPIX  (B_*N_*HW)          // 16896
#define NX    128
#define BEV_ELEMS (B_*CT*NX*NX)   // 4,194,304
#define DEPTH_OFF BEV_ELEMS

// ws layout (float offsets). Double region first (8B aligned at base).
#define TDREC   40
#define WS_WT   1920                       // transposed weight [512][128]
#define WS_OUT  (WS_WT + CIN*OP)           // [16896][128] conv output
#define WS_PS   (WS_OUT + NPIX*OP)         // p-slab [bw][59][96]
#define WS_C    (WS_PS + B_*FW*DEPN*96)    // group sums [bw][59][64]
#define WS_VOX  (WS_C + B_*FW*DEPN*64)     // int [bw][59]

// ---------------- K0: weight transpose + per-(b,n) f64 transforms ----------------
__device__ inline void inv3d(const double* m, double* o) {
    #pragma clang fp contract(off)
    double c00 = m[4]*m[8] - m[5]*m[7];
    double c01 = m[5]*m[6] - m[3]*m[8];
    double c02 = m[3]*m[7] - m[4]*m[6];
    double det = m[0]*c00 + m[1]*c01 + m[2]*c02;
    o[0] = c00/det; o[1] = (m[2]*m[7]-m[1]*m[8])/det; o[2] = (m[1]*m[5]-m[2]*m[4])/det;
    o[3] = c01/det; o[4] = (m[0]*m[8]-m[2]*m[6])/det; o[5] = (m[2]*m[3]-m[0]*m[5])/det;
    o[6] = c02/det; o[7] = (m[1]*m[6]-m[0]*m[7])/det; o[8] = (m[0]*m[4]-m[1]*m[3])/det;
}
__device__ inline void mm3d(const double* a, const double* b, double* o) {
    #pragma clang fp contract(off)
    for (int i = 0; i < 3; ++i)
        for (int k = 0; k < 3; ++k)
            o[i*3+k] = (a[i*3+0]*b[0*3+k] + a[i*3+1]*b[1*3+k]) + a[i*3+2]*b[2*3+k];
}

__global__ void k0_prep(const float* __restrict__ rots, const float* __restrict__ trans,
                        const float* __restrict__ intr, const float* __restrict__ prots,
                        const float* __restrict__ ptrans, const float* __restrict__ bda,
                        const float* __restrict__ W, float* __restrict__ ws) {
    int tid = blockIdx.x * 256 + threadIdx.x;
    int stride = gridDim.x * 256;
    for (int i = tid; i < CIN * OP; i += stride) {
        int c = i >> 7, o = i & 127;
        ws[WS_WT + i] = (o < NOUT) ? W[o * CIN + c] : 0.0f;
    }
    if (blockIdx.x == 0 && threadIdx.x < B_ * N_) {
        #pragma clang fp contract(off)
        int t = threadIdx.x;
        int b = t / N_;
        double* X = (double*)(ws) + t * TDREC;
        double PR[9], Kd[9], Rd[9], Bd[9];
        for (int i = 0; i < 9; ++i) PR[i] = (double)prots[t * 9 + i];
        for (int i = 0; i < 9; ++i) Kd[i] = (double)intr[t * 9 + i];
        for (int i = 0; i < 9; ++i) Rd[i] = (double)rots[t * 9 + i];
        for (int i = 0; i < 9; ++i) Bd[i] = (double)bda[b * 9 + i];
        double iPR[9]; inv3d(PR, iPR);
        for (int i = 0; i < 9; ++i) X[i] = iPR[i];
        for (int i = 0; i < 3; ++i) X[9 + i] = (double)ptrans[t * 3 + i];
        double iK[9];  inv3d(Kd, iK);
        double comb[9]; mm3d(Rd, iK, comb);
        for (int i = 0; i < 9; ++i) X[12 + i] = comb[i];
        for (int i = 0; i < 3; ++i) X[21 + i] = (double)trans[t * 3 + i];
        for (int i = 0; i < 9; ++i) X[24 + i] = Bd[i];
    }
}

// ---------------- K1: 1x1 conv GEMM ----------------
__global__ __launch_bounds__(256) void k1_gemm(const float* __restrict__ x,
                                               const float* __restrict__ bias,
                                               float* __restrict__ ws) {
    __shared__ float sx[32][32];
    __shared__ float sw[32][128];
    const int tid = threadIdx.x;
    const int og4 = (tid & 31) * 4;
    const int pg4 = (tid >> 5) * 4;
    const int bn = blockIdx.y;
    const int hwbase = blockIdx.x * 32;
    const float* xg = x + (size_t)bn * CIN * HW + hwbase;
    const float* wT = ws + WS_WT;
    float acc[4][4] = {};
    for (int ck = 0; ck < CIN; ck += 32) {
        __syncthreads();
        {
            int r = tid >> 3, c4 = (tid & 7) * 4;
            *(float4*)&sx[r][c4] = *(const float4*)(xg + (size_t)(ck + r) * HW + c4);
        }
        {
            int o4 = (tid & 31) * 4, rb = tid >> 5;
            #pragma unroll
            for (int rr = 0; rr < 4; ++rr) {
                int r = rb + rr * 8;
                *(float4*)&sw[r][o4] = *(const float4*)(wT + (size_t)(ck + r) * OP + o4);
            }
        }
        __syncthreads();
        #pragma unroll
        for (int cc = 0; cc < 32; ++cc) {
            const float4 wv = *(const float4*)&sw[cc][og4];
            const float4 xv = *(const float4*)&sx[cc][pg4];
            acc[0][0] = fmaf(xv.x, wv.x, acc[0][0]); acc[0][1] = fmaf(xv.x, wv.y, acc[0][1]);
            acc[0][2] = fmaf(xv.x, wv.z, acc[0][2]); acc[0][3] = fmaf(xv.x, wv.w, acc[0][3]);
            acc[1][0] = fmaf(xv.y, wv.x, acc[1][0]); acc[1][1] = fmaf(xv.y, wv.y, acc[1][1]);
            acc[1][2] = fmaf(xv.y, wv.z, acc[1][2]); acc[1][3] = fmaf(xv.y, wv.w, acc[1][3]);
            acc[2][0] = fmaf(xv.z, wv.x, acc[2][0]); acc[2][1] = fmaf(xv.z, wv.y, acc[2][1]);
            acc[2][2] = fmaf(xv.z, wv.z, acc[2][2]); acc[2][3] = fmaf(xv.z, wv.w, acc[2][3]);
            acc[3][0] = fmaf(xv.w, wv.x, acc[3][0]); acc[3][1] = fmaf(xv.w, wv.y, acc[3][1]);
            acc[3][2] = fmaf(xv.w, wv.z, acc[3][2]); acc[3][3] = fmaf(xv.w, wv.w, acc[3][3]);
        }
    }
    float bb[4];
    #pragma unroll
    for (int j = 0; j < 4; ++j) bb[j] = (og4 + j < NOUT) ? bias[og4 + j] : 0.0f;
    float* out = ws + WS_OUT;
    #pragma unroll
    for (int i = 0; i < 4; ++i) {
        size_t pix = (size_t)bn * HW + hwbase + pg4 + i;
        float4 st = { acc[i][0] + bb[0], acc[i][1] + bb[1], acc[i][2] + bb[2], acc[i][3] + bb[3] };
        *(float4*)(out + pix * OP + og4) = st;
    }
}

// ---------------- K2b: fused softmax + geometry + group-GEMM ----------------
// Block per (b,w). Stages 96 conv rows, softmax in-LDS, f64 geometry (validated
// bit-exact chain), then C[59][64] = P^T x F via register-tiled LDS GEMM.
// No global atomics on the fast path (dense C scratch; k2c reduces).
__global__ __launch_bounds__(256) void k2b_fused(float* __restrict__ ws,
                                                 float* __restrict__ dout) {
    __shared__ float sRow[96][124];            // conv rows -> p (cols 0..58) + feats (59..122)
    __shared__ unsigned short sv16[DEPN * 96]; // per-(d,j) voxel id or 0xFFFF
    __shared__ double sT[N_ * TDREC];
    __shared__ int sflag[DEPN];
    const int tid = threadIdx.x;
    const int bw = blockIdx.x;
    const int b = bw / FW, w = bw - b * FW;

    // A: stage conv rows (cols 0..123) + transforms
    {
        const float* outbase = ws + WS_OUT;
        for (int i = tid; i < 96 * 31; i += 256) {
            int r = i / 31, c4 = (i - r * 31) * 4;
            int n = r >> 4, h = r & 15;
            size_t pix = (size_t)(b * N_ + n) * HW + (size_t)h * FW + w;
            *(float4*)&sRow[r][c4] = *(const float4*)(outbase + pix * OP + c4);
        }
        if (tid < N_ * TDREC) sT[tid] = ((const double*)ws)[b * (N_ * TDREC) + tid];
    }
    __syncthreads();

    // B: softmax per row (one wave handles 24 rows)
    {
        const int lane = tid & 63;
        for (int r = (tid >> 6) * 24; r < (tid >> 6) * 24 + 24; ++r) {
            float v = (lane < DEPN) ? sRow[r][lane] : -INFINITY;
            float m = v;
            #pragma unroll
            for (int off = 32; off > 0; off >>= 1) m = fmaxf(m, __shfl_xor(m, off, 64));
            float e = (lane < DEPN) ? expf(v - m) : 0.0f;
            float s = e;
            #pragma unroll
            for (int off = 32; off > 0; off >>= 1) s += __shfl_xor(s, off, 64);
            if (lane < DEPN) sRow[r][lane] = e / s;
        }
    }
    __syncthreads();

    // C: dump p-slab [d][j] to ws (coalesced; feeds k2d depth transpose)
    {
        float* ps = ws + WS_PS + (size_t)bw * (DEPN * 96);
        for (int idx = tid; idx < DEPN * 96; idx += 256) {
            int d = idx / 96, j = idx - d * 96;
            ps[idx] = sRow[j][d];
        }
    }
    // D: geometry, item-parallel over (d,j). Bit-exact validated f64 chain.
    {
        #pragma clang fp contract(off)
        const double xs = (w == 43) ? 703.0 : (double)w * (703.0 / 43.0);
        const double BXY = (double)(-51.2000007629394531f);  // f32 value of BX-DX/2
        for (int idx = tid; idx < DEPN * 96; idx += 256) {
            int d = idx / 96, j = idx - d * 96;
            int n = j >> 4, h = j & 15;
            const double* T = &sT[n * TDREC];
            const double ys = (double)(h * 17);
            const double u0 = xs - T[9];
            const double u1 = ys - T[10];
            const double u2 = (double)(d + 1) - T[11];
            const double p0 = (T[0]*u0 + T[1]*u1) + T[2]*u2;
            const double p1 = (T[3]*u0 + T[4]*u1) + T[5]*u2;
            const double p2 = (T[6]*u0 + T[7]*u1) + T[8]*u2;
            const double q0 = p0 * p2, q1 = p1 * p2, q2 = p2;
            const double r0 = ((T[12]*q0 + T[13]*q1) + T[14]*q2) + T[21];
            const double r1 = ((T[15]*q0 + T[16]*q1) + T[17]*q2) + T[22];
            const double r2 = ((T[18]*q0 + T[19]*q1) + T[20]*q2) + T[23];
            const double g0 = (T[24]*r0 + T[25]*r1) + T[26]*r2;
            const double g1 = (T[27]*r0 + T[28]*r1) + T[29]*r2;
            const double g2 = (T[30]*r0 + T[31]*r1) + T[32]*r2;
            const double fx = floor((g0 - BXY) / 0.8);
            const double fy = floor((g1 - BXY) / 0.8);
            // z-bin: compare form (margin 0.026 >> ulp; equiv to floor((g2+10)/20)==0)
            const bool keep = (fx >= 0.0) & (fx < 128.0) & (fy >= 0.0) & (fy < 128.0) &
                              (g2 >= -10.0) & (g2 < 10.0);
            sv16[idx] = keep ? (unsigned short)((int)fx * NX + (int)fy) : (unsigned short)0xFFFF;
        }
    }
    __syncthreads();

    // E: per-d uniformity flags + mask dropped p's to zero
    if (tid < DEPN) {
        int u = -1; bool mix = false;
        for (int j = 0; j < 96; ++j) {
            int v = sv16[tid * 96 + j];
            if (v != 0xFFFF) { if (u < 0) u = v; else if (v != u) mix = true; }
        }
        sflag[tid] = mix ? -2 : u;
        ((int*)(ws + WS_VOX))[bw * DEPN + tid] = mix ? -1 : u;
    }
    for (int idx = tid; idx < DEPN * 96; idx += 256) {
        if (sv16[idx] == 0xFFFF) {
            int d = idx / 96, j = idx - d * 96;
            sRow[j][d] = 0.0f;
        }
    }
    __syncthreads();

    // F: C[d][c] = sum_j p[j][d] * f[j][c], 4x4 register tile per thread
    const int di = tid >> 4, ci = tid & 15;
    float acc[4][4] = {};
    for (int j = 0; j < 96; ++j) {
        const float4 pv = *(const float4*)&sRow[j][4 * di];
        const float pp[4] = { pv.x, pv.y, pv.z, pv.w };
        const float* fr = &sRow[j][DEPN + 4 * ci];
        const float ff[4] = { fr[0], fr[1], fr[2], fr[3] };
        #pragma unroll
        for (int rd = 0; rd < 4; ++rd)
            #pragma unroll
            for (int rc = 0; rc < 4; ++rc)
                acc[rd][rc] = fmaf(pp[rd], ff[rc], acc[rd][rc]);
    }
    // G: store C (coalesced) + rare per-point slow path for mixed groups
    {
        float* cg = ws + WS_C + (size_t)bw * (DEPN * 64);
        #pragma unroll
        for (int rd = 0; rd < 4; ++rd) {
            int d = 4 * di + rd;
            if (d < DEPN) {
                float4 st = { acc[rd][0], acc[rd][1], acc[rd][2], acc[rd][3] };
                *(float4*)&cg[d * 64 + 4 * ci] = st;
            }
        }
    }
    for (int d = 0; d < DEPN; ++d) {
        if (sflag[d] == -2) {  // mixed-voxel group: per-point atomics (none for these inputs)
            int c = tid & 63, g = tid >> 6;
            for (int jj = 0; jj < 24; ++jj) {
                int j = g * 24 + jj;
                int v = sv16[d * 96 + j];
                if (v != 0xFFFF)
                    atomicAdd(dout + (((size_t)(b * CT + c)) << 14) + v,
                              sRow[j][d] * sRow[j][DEPN + c]);
            }
        }
    }
}

// ---------------- K2c: per-(b,d) voxel reduction, line-private atomics ----------------
__global__ __launch_bounds__(256) void k2c_reduce(const float* __restrict__ ws,
                                                  float* __restrict__ dout) {
    __shared__ float acc[FW][64];
    __shared__ int tags[FW];
    __shared__ unsigned char slot[FW];
    __shared__ int wvox[FW];
    __shared__ int nsh;
    const int d = blockIdx.x, b = blockIdx.y;
    const int tid = threadIdx.x;
    if (tid < FW) wvox[tid] = ((const int*)(ws + WS_VOX))[(b * FW + tid) * DEPN + d];
    for (int i = tid; i < FW * 64; i += 256) (&acc[0][0])[i] = 0.0f;
    __syncthreads();
    if (tid < 64) {  // wave 0: dedup voxel ids into slots
        const int lane = tid;
        int v = (lane < FW) ? wvox[lane] : -1;
        int firstw = lane;
        for (int w2 = 0; w2 < FW; ++w2) {
            int vw = __shfl(v, w2, 64);
            if (v >= 0 && vw == v && w2 < firstw) firstw = w2;
        }
        unsigned long long leaders = __ballot(v >= 0 && firstw == lane);
        if (lane < FW) {
            if (v >= 0) {
                int s = __popcll(leaders & ((1ull << firstw) - 1ull));
                slot[lane] = (unsigned char)s;
                if (firstw == lane) tags[s] = v;
            } else slot[lane] = 255;
        }
        if (lane == 0) nsh = __popcll(leaders);
    }
    __syncthreads();
    const int c = tid & 63, g = tid >> 6;
    for (int w = g; w < FW; w += 4) {
        if (wvox[w] >= 0) {
            float v = ws[WS_C + ((size_t)(b * FW + w) * DEPN + d) * 64 + c];
            atomicAdd(&acc[slot[w]][c], v);
        }
    }
    __syncthreads();
    const int ns = nsh;
    for (int s = g; s < ns; s += 4)
        atomicAdd(dout + (((size_t)(b * CT + c)) << 14) + tags[s], acc[s][c]);
}

// ---------------- K2d: depth output transpose (coalesced full-line writes) ---------
__global__ __launch_bounds__(256) void k2d_depth(const float* __restrict__ ws,
                                                 float* __restrict__ dout) {
    const int d = blockIdx.x, bn = blockIdx.y;
    const int b = bn / N_, n = bn - b * N_;
    const int tid = threadIdx.x;
    for (int t = tid; t < HW; t += 256) {
        int h = t / FW, w = t - h * FW;
        float p = ws[WS_PS + ((size_t)(b * FW + w) * DEPN + d) * 96 + n * FH + h];
        dout[DEPTH_OFF + ((size_t)bn * DEPN + d) * HW + t] = p;
    }
}

// ---------------- launcher ----------------
extern "C" void kernel_launch(void* const* d_in, const int* in_sizes, int n_in,
                              void* d_out, int out_size, void* d_ws, size_t ws_size,
                              hipStream_t stream) {
    const float* x      = (const float*)d_in[0];
    const float* rots   = (const float*)d_in[1];
    const float* trans  = (const float*)d_in[2];
    const float* intr   = (const float*)d_in[3];
    const float* prots  = (const float*)d_in[4];
    const float* ptrans = (const float*)d_in[5];
    const float* bda    = (const float*)d_in[6];
    const float* W      = (const float*)d_in[7];
    const float* bias   = (const float*)d_in[8];
    float* out = (float*)d_out;
    float* ws  = (float*)d_ws;

    hipMemsetAsync(d_out, 0, (size_t)BEV_ELEMS * sizeof(float), stream);
    k0_prep<<<128, 256, 0, stream>>>(rots, trans, intr, prots, ptrans, bda, W, ws);
    k1_gemm<<<dim3(HW / 32, B_ * N_), 256, 0, stream>>>(x, bias, ws);
    k2b_fused<<<B_ * FW, 256, 0, stream>>>(ws, out);
    k2c_reduce<<<dim3(DEPN, B_), 256, 0, stream>>>(ws, out);
    k2d_depth<<<dim3(DEPN, B_ * N_), 256, 0, stream>>>(ws, out);
}